// Round 2
// baseline (23974.417 us; speedup 1.0000x reference)
//
#include <hip/hip_runtime.h>
#include <stdint.h>

#define LL 2048
#define BB 8
#define DD 768
#define NROWS (LL*BB)
#define TQ 8
#define TM 64
#define DC 64
#define QKSCALE 0.03608439182435161f   // 1/sqrt(768)

__device__ __forceinline__ float bf2f(unsigned short u) {
    union { unsigned int u; float f; } c; c.u = ((unsigned int)u) << 16; return c.f;
}
__device__ __forceinline__ unsigned short f2bf(float f) {
    union { float f; unsigned int u; } c; c.f = f;
    unsigned int x = c.u;
    return (unsigned short)((x + 0x7fffu + ((x >> 16) & 1u)) >> 16);
}

// One cross-attention branch, fully fused (f32 inputs):
//   scores = q @ kv^T * scale ; p = softmax(scores) ; ctx = p @ kv ;
//   y = ctx @ W^T + bias ; y -> ws (bf16) ; atomics accumulate BN stats.
// Layouts: q, kv are [L, B, D] f32. W is [D(out), D(in)] f32.
__global__ __launch_bounds__(256)
void branch_kernel(const float* __restrict__ q,
                   const float* __restrict__ kv,
                   const float* __restrict__ W,
                   const float* __restrict__ bias,
                   unsigned short* __restrict__ y_out,
                   float* __restrict__ stats)   // [2*DD]: sum, sumsq
{
    __shared__ float qs[TQ * DD];               // 24 KB  f32 q rows
    __shared__ float smem[TQ * LL / 2];         // 32 KB: scores (bf16 view) then ctx f32 overlay
    __shared__ float kvch[TM][DC + 1];          // 16.25 KB staged kv / W chunk (pad 65)

    const int tid = threadIdx.x;
    const int b  = blockIdx.y;
    const int l0 = blockIdx.x * TQ;
    unsigned short* scb = (unsigned short*)smem;

    // ---- stage q rows (f32, vectorized) ----
    for (int i = tid; i < TQ * DD / 4; i += 256) {
        int r  = i / (DD / 4);
        int d4 = i - r * (DD / 4);
        float4 v = *(const float4*)&q[((size_t)(l0 + r) * BB + b) * DD + d4 * 4];
        float* dst = &qs[r * DD + d4 * 4];
        dst[0] = v.x; dst[1] = v.y; dst[2] = v.z; dst[3] = v.w;
    }
    __syncthreads();

    const int lane = tid & 63;
    const int wv   = tid >> 6;          // wave 0..3
    const int r0 = 2 * wv, r1 = 2 * wv + 1;

    // ---- Phase 1: scores[r][m] ----
    for (int mt = 0; mt < LL / TM; ++mt) {
        float acc0 = 0.f, acc1 = 0.f;
        for (int dc = 0; dc < DD / DC; ++dc) {
            __syncthreads();
            for (int i = tid; i < TM * DC / 4; i += 256) {
                int mm = i >> 4;
                int d4 = i & 15;
                float4 v = *(const float4*)&kv[((size_t)(mt * TM + mm) * BB + b) * DD + dc * DC + d4 * 4];
                float* dst = &kvch[mm][d4 * 4];
                dst[0] = v.x; dst[1] = v.y; dst[2] = v.z; dst[3] = v.w;
            }
            __syncthreads();
            const float* qp0 = &qs[r0 * DD + dc * DC];
            const float* qp1 = &qs[r1 * DD + dc * DC];
            #pragma unroll 8
            for (int dd2 = 0; dd2 < DC; ++dd2) {
                float kvv = kvch[lane][dd2];
                acc0 = fmaf(qp0[dd2], kvv, acc0);
                acc1 = fmaf(qp1[dd2], kvv, acc1);
            }
        }
        scb[r0 * LL + mt * TM + lane] = f2bf(acc0 * QKSCALE);
        scb[r1 * LL + mt * TM + lane] = f2bf(acc1 * QKSCALE);
    }
    __syncthreads();

    // ---- Softmax: wave w owns rows 2w, 2w+1; keep 1/sum in regs ----
    float invs[2];
    for (int rp = 0; rp < 2; ++rp) {
        const int rr = 2 * wv + rp;
        unsigned short* srow = &scb[rr * LL];
        float mx = -1e30f;
        for (int m = lane; m < LL; m += 64) mx = fmaxf(mx, bf2f(srow[m]));
        for (int off = 32; off > 0; off >>= 1) mx = fmaxf(mx, __shfl_xor(mx, off));
        float sum = 0.f;
        for (int m = lane; m < LL; m += 64) {
            float p = __expf(bf2f(srow[m]) - mx);
            srow[m] = f2bf(p);          // store unnormalized p
            sum += p;
        }
        for (int off = 32; off > 0; off >>= 1) sum += __shfl_xor(sum, off);
        invs[rp] = 1.0f / sum;
    }
    __syncthreads();

    // ---- Phase 2: ctx[r][d] = (1/sum) * sum_m p[r][m] kv[m][d] ----
    const int r2  = tid >> 5;           // 0..7 (wave w lanes 0-31 -> 2w, 32-63 -> 2w+1)
    const int dlo = tid & 31;
    const float pinv = (lane < 32) ? invs[0] : invs[1];
    float ctxacc[2 * (DD / DC)];        // 24 accumulators: d = 32*j + dlo
    #pragma unroll
    for (int j = 0; j < 2 * (DD / DC); ++j) ctxacc[j] = 0.f;

    for (int mt = 0; mt < LL / TM; ++mt) {
        const unsigned short* prow = &scb[r2 * LL + mt * TM];
        for (int dc = 0; dc < DD / DC; ++dc) {
            __syncthreads();
            for (int i = tid; i < TM * DC / 4; i += 256) {
                int mm = i >> 4;
                int d4 = i & 15;
                float4 v = *(const float4*)&kv[((size_t)(mt * TM + mm) * BB + b) * DD + dc * DC + d4 * 4];
                float* dst = &kvch[mm][d4 * 4];
                dst[0] = v.x; dst[1] = v.y; dst[2] = v.z; dst[3] = v.w;
            }
            __syncthreads();
            float a0 = 0.f, a1 = 0.f;
            #pragma unroll 8
            for (int mm = 0; mm < TM; ++mm) {
                float p = bf2f(prow[mm]);
                a0 = fmaf(p, kvch[mm][dlo],      a0);
                a1 = fmaf(p, kvch[mm][32 + dlo], a1);
            }
            ctxacc[2 * dc]     += a0;
            ctxacc[2 * dc + 1] += a1;
        }
    }
    __syncthreads();
    float* ctx = smem;                  // overlay onto dead score region (24 KB of 32 KB)
    #pragma unroll
    for (int j = 0; j < 2 * (DD / DC); ++j)
        ctx[r2 * DD + 32 * j + dlo] = ctxacc[j] * pinv;
    __syncthreads();

    // ---- Conv1x1 (+bias) + BN stat atomics ----
    const size_t yrow = ((size_t)(l0 + r2) * BB + b) * DD;
    for (int et = 0; et < DD / 64; ++et) {
        float y0 = 0.f, y1 = 0.f;
        for (int dc = 0; dc < DD / DC; ++dc) {
            __syncthreads();
            for (int i = tid; i < 64 * DC / 4; i += 256) {
                int ee = i >> 4;
                int d4 = i & 15;
                float4 v = *(const float4*)&W[(size_t)(et * 64 + ee) * DD + dc * DC + d4 * 4];
                float* dst = &kvch[ee][d4 * 4];
                dst[0] = v.x; dst[1] = v.y; dst[2] = v.z; dst[3] = v.w;
            }
            __syncthreads();
            const float* cp = &ctx[r2 * DD + dc * DC];
            #pragma unroll 8
            for (int dd2 = 0; dd2 < DC; ++dd2) {
                float cv = cp[dd2];
                y0 = fmaf(cv, kvch[dlo][dd2],      y0);
                y1 = fmaf(cv, kvch[32 + dlo][dd2], y1);
            }
        }
        const int e0 = et * 64 + dlo;
        const int e1 = e0 + 32;
        float v0 = y0 + bias[e0];
        float v1 = y1 + bias[e1];
        y_out[yrow + e0] = f2bf(v0);
        y_out[yrow + e1] = f2bf(v1);
        atomicAdd(&stats[e0], v0);
        atomicAdd(&stats[e1], v1);
        atomicAdd(&stats[DD + e0], v0 * v0);
        atomicAdd(&stats[DD + e1], v1 * v1);
    }
}

// Fold batch stats -> per-channel scale/shift. <<<2, 768>>> (x: 0=a, 1=v)
__global__ void bn_params(const float* __restrict__ stats_a, const float* __restrict__ stats_v,
                          const float* __restrict__ g_a, const float* __restrict__ be_a,
                          const float* __restrict__ g_v, const float* __restrict__ be_v,
                          float* __restrict__ bnp_a, float* __restrict__ bnp_v)
{
    const int e = threadIdx.x;
    const float* st = (blockIdx.x == 0) ? stats_a : stats_v;
    const float* g  = (blockIdx.x == 0) ? g_a  : g_v;
    const float* be = (blockIdx.x == 0) ? be_a : be_v;
    float* bnp = (blockIdx.x == 0) ? bnp_a : bnp_v;
    float mean = st[e] * (1.0f / NROWS);
    float var  = st[DD + e] * (1.0f / NROWS) - mean * mean;
    float scale = g[e] * rsqrtf(var + 1e-5f);
    bnp[e]      = scale;
    bnp[DD + e] = be[e] - mean * scale;
}

// BN affine + PReLU (x2) + residual + row LayerNorm -> f32 out. One block per (l,b) row.
__global__ __launch_bounds__(256)
void final_kernel(const float* __restrict__ x,
                  const unsigned short* __restrict__ y_a, const unsigned short* __restrict__ y_v,
                  const float* __restrict__ bnp_a, const float* __restrict__ bnp_v,
                  const float* __restrict__ pra, const float* __restrict__ prv,
                  const float* __restrict__ lng, const float* __restrict__ lnb,
                  float* __restrict__ out)
{
    const int n = blockIdx.x;
    const int tid = threadIdx.x;
    __shared__ float vrow[DD];
    __shared__ float reds[4], reds2[4];
    const float aa = pra[0];
    const float av = prv[0];
    const size_t base = (size_t)n * DD;
    float s = 0.f, s2 = 0.f;
    for (int e = tid; e < DD; e += 256) {
        float ya = bf2f(y_a[base + e]) * bnp_a[e] + bnp_a[DD + e];
        ya = ya > 0.f ? ya : aa * ya;
        float yv = bf2f(y_v[base + e]) * bnp_v[e] + bnp_v[DD + e];
        yv = yv > 0.f ? yv : av * yv;
        float v = x[base + e] + ya + yv;
        vrow[e] = v;
        s += v; s2 += v * v;
    }
    for (int off = 32; off > 0; off >>= 1) { s += __shfl_xor(s, off); s2 += __shfl_xor(s2, off); }
    const int wv = tid >> 6;
    if ((tid & 63) == 0) { reds[wv] = s; reds2[wv] = s2; }
    __syncthreads();
    float ts  = reds[0] + reds[1] + reds[2] + reds[3];
    float ts2 = reds2[0] + reds2[1] + reds2[2] + reds2[3];
    float mean = ts * (1.0f / DD);
    float var  = ts2 * (1.0f / DD) - mean * mean;
    float rstd = rsqrtf(var + 1e-5f);
    for (int e = tid; e < DD; e += 256) {
        float o = (vrow[e] - mean) * rstd * lng[e] + lnb[e];
        out[base + e] = o;
    }
}

extern "C" void kernel_launch(void* const* d_in, const int* in_sizes, int n_in,
                              void* d_out, int out_size, void* d_ws, size_t ws_size,
                              hipStream_t stream)
{
    const float* x_a    = (const float*)d_in[0];
    const float* x_v    = (const float*)d_in[1];
    const float* x      = (const float*)d_in[2];
    const float* W_a    = (const float*)d_in[3];
    const float* b_a    = (const float*)d_in[4];
    const float* bn_a_g = (const float*)d_in[5];
    const float* bn_a_b = (const float*)d_in[6];
    const float* pr_a   = (const float*)d_in[7];
    const float* W_v    = (const float*)d_in[8];
    const float* b_v    = (const float*)d_in[9];
    const float* bn_v_g = (const float*)d_in[10];
    const float* bn_v_b = (const float*)d_in[11];
    const float* pr_v   = (const float*)d_in[12];
    const float* ln_g   = (const float*)d_in[13];
    const float* ln_b   = (const float*)d_in[14];

    float* ws = (float*)d_ws;
    float* stats_a = ws;              // 1536 f32
    float* stats_v = ws + 1536;       // 1536 f32
    float* bnp_a   = ws + 3072;       // 1536 f32
    float* bnp_v   = ws + 4608;       // 1536 f32
    unsigned short* y_a = (unsigned short*)(ws + 8192);             // [NROWS*DD] bf16
    unsigned short* y_v = y_a + (size_t)NROWS * DD;                 // [NROWS*DD] bf16
    // total ws use: 32 KB + 2 * 24 MB ≈ 48.4 MB

    hipMemsetAsync(stats_a, 0, 3072 * sizeof(float), stream);       // zero BN stat accumulators

    dim3 bgrid(LL / TQ, BB);
    branch_kernel<<<bgrid, 256, 0, stream>>>(x, x_a, W_a, b_a, y_a, stats_a);
    branch_kernel<<<bgrid, 256, 0, stream>>>(x, x_v, W_v, b_v, y_v, stats_v);
    bn_params<<<2, 768, 0, stream>>>(stats_a, stats_v, bn_a_g, bn_a_b, bn_v_g, bn_v_b, bnp_a, bnp_v);
    final_kernel<<<NROWS, 256, 0, stream>>>(x, y_a, y_v, bnp_a, bnp_v, pr_a, pr_v, ln_g, ln_b,
                                            (float*)d_out);
}

// Round 3
// 780.279 us; speedup vs baseline: 30.7254x; 30.7254x over previous
//
#include <hip/hip_runtime.h>
#include <stdint.h>

#define LL 2048
#define BB 8
#define DD 768
#define NROWS (LL*BB)
#define QKSCALE 0.03608439182435161f   // 1/sqrt(768)
#define KP 40                          // LDS k-stride (bf16 elems), padded vs 32
#define EP 72                          // epilogue LDS row stride (bf16 elems)

typedef __attribute__((ext_vector_type(8))) short short8;
typedef __attribute__((ext_vector_type(4))) float f32x4;
typedef unsigned short u16;
typedef unsigned int u32;

__device__ __forceinline__ float bf2f(u16 u) {
    union { u32 u; float f; } c; c.u = ((u32)u) << 16; return c.f;
}
__device__ __forceinline__ u16 f2bf(float f) {
    union { float f; u32 u; } c; c.f = f;
    return (u16)((c.u + 0x8000u) >> 16);
}
__device__ __forceinline__ u32 pack_bf2(float a, float b) {
    union { float f; u32 u; } x, y; x.f = a; y.f = b;
    return ((x.u + 0x8000u) >> 16) | ((y.u + 0x8000u) & 0xffff0000u);
}

// Stage a 128x32 tile (rows at stride ld, k-offset kt) into LDS bf16 [128][KP].
// src must be pre-offset to the tile's first row. f32 source converts in-flight.
template<typename T>
__device__ __forceinline__ void stage(u16* __restrict__ dst, const T* __restrict__ src,
                                      long ld, int kt, int tid) {
    #pragma unroll
    for (int j = 0; j < 4; ++j) {
        int idx = tid + 256 * j;
        int row = idx >> 3, c4 = idx & 7;
        if constexpr (sizeof(T) == 4) {
            const float4 v = *(const float4*)(src + (size_t)row * ld + kt + c4 * 4);
            uint2 o; o.x = pack_bf2(v.x, v.y); o.y = pack_bf2(v.z, v.w);
            *(uint2*)&dst[row * KP + c4 * 4] = o;
        } else {
            *(uint2*)&dst[row * KP + c4 * 4] = *(const uint2*)(src + (size_t)row * ld + kt + c4 * 4);
        }
    }
}

// C = A @ B^T over K, 128x128 tile per block, 256 threads (2x2 waves of 64x64).
// A: [M,K] rows at stride lda (+ z*astr). B: [N,K] rows at stride ldb (+ z*bstr).
// C: bf16 [M,N] at stride ldc (+ z*cstr).
// EPI 0: plain store (U^T).  EPI 1: v=exp(v*QKSCALE), row-sum atomics to lsum.
// EPI 2: v=v*(1/lsum[row]) + bias[col]; BN col-stat atomics to stats.
template<int EPI, typename TA, typename TB>
__global__ __launch_bounds__(256)
void gemm_bt(const TA* __restrict__ A, int lda, long astr,
             const TB* __restrict__ B, int ldb, long bstr,
             u16* __restrict__ C, long cstr, int ldc,
             int K,
             float* __restrict__ lsum,
             const float* __restrict__ bias,
             float* __restrict__ stats)
{
    __shared__ u16 lds[18432];          // 36.9 KB: As(5120) + Bs(5120) in loop; 4x64x72 epilogue
    u16* As = lds;
    u16* Bs = lds + 128 * KP;

    const int tid = threadIdx.x;
    const int z = blockIdx.z;
    const int m0 = blockIdx.y * 128, n0 = blockIdx.x * 128;
    const TA* Ab = A + (size_t)z * astr + (size_t)m0 * lda;
    const TB* Bb = B + (size_t)z * bstr + (size_t)n0 * ldb;
    u16* Cb = C + (size_t)z * cstr;

    const int lane = tid & 63, w = tid >> 6;
    const int wm = w >> 1, wn = w & 1;
    const int lr = lane & 15, lg = lane >> 4;

    f32x4 acc[4][4];
    const f32x4 zz = {0.f, 0.f, 0.f, 0.f};
    #pragma unroll
    for (int i = 0; i < 4; ++i)
        #pragma unroll
        for (int j = 0; j < 4; ++j) acc[i][j] = zz;

    for (int kt = 0; kt < K; kt += 32) {
        __syncthreads();
        stage<TA>(As, Ab, lda, kt, tid);
        stage<TB>(Bs, Bb, ldb, kt, tid);
        __syncthreads();
        short8 af[4], bf[4];
        #pragma unroll
        for (int mi = 0; mi < 4; ++mi)
            af[mi] = *(const short8*)&As[(wm * 64 + mi * 16 + lr) * KP + lg * 8];
        #pragma unroll
        for (int ni = 0; ni < 4; ++ni)
            bf[ni] = *(const short8*)&Bs[(wn * 64 + ni * 16 + lr) * KP + lg * 8];
        #pragma unroll
        for (int mi = 0; mi < 4; ++mi)
            #pragma unroll
            for (int ni = 0; ni < 4; ++ni)
                acc[mi][ni] = __builtin_amdgcn_mfma_f32_16x16x32_bf16(af[mi], bf[ni], acc[mi][ni], 0, 0, 0);
    }

    // ---- epilogue: frags -> per-wave LDS tile (64x72) -> coalesced bf16 stores ----
    __syncthreads();
    u16* eb = lds + w * (64 * EP);

    float invl[4][4]; float bcol[4];
    if constexpr (EPI == 2) {
        #pragma unroll
        for (int mi = 0; mi < 4; ++mi)
            #pragma unroll
            for (int r = 0; r < 4; ++r)
                invl[mi][r] = 1.0f / lsum[z * 2048 + m0 + wm * 64 + mi * 16 + lg * 4 + r];
        #pragma unroll
        for (int ni = 0; ni < 4; ++ni)
            bcol[ni] = bias[n0 + wn * 64 + ni * 16 + lr];
    }
    float csum[4] = {0, 0, 0, 0}, csq[4] = {0, 0, 0, 0};

    #pragma unroll
    for (int mi = 0; mi < 4; ++mi) {
        float rsum[4] = {0, 0, 0, 0};
        #pragma unroll
        for (int ni = 0; ni < 4; ++ni) {
            #pragma unroll
            for (int r = 0; r < 4; ++r) {
                float v = acc[mi][ni][r];
                if constexpr (EPI == 1) { v = __expf(v * QKSCALE); rsum[r] += v; }
                if constexpr (EPI == 2) { v = v * invl[mi][r] + bcol[ni]; csum[ni] += v; csq[ni] += v * v; }
                eb[(mi * 16 + lg * 4 + r) * EP + ni * 16 + lr] = f2bf(v);
            }
        }
        if constexpr (EPI == 1) {
            #pragma unroll
            for (int r = 0; r < 4; ++r) {
                float s = rsum[r];
                s += __shfl_xor(s, 1); s += __shfl_xor(s, 2);
                s += __shfl_xor(s, 4); s += __shfl_xor(s, 8);
                if (lr == 0)
                    atomicAdd(&lsum[z * 2048 + m0 + wm * 64 + mi * 16 + lg * 4 + r], s);
            }
        }
    }
    if constexpr (EPI == 2) {
        #pragma unroll
        for (int ni = 0; ni < 4; ++ni) {
            float s = csum[ni], q = csq[ni];
            s += __shfl_xor(s, 16); s += __shfl_xor(s, 32);
            q += __shfl_xor(q, 16); q += __shfl_xor(q, 32);
            if (lg == 0) {
                atomicAdd(&stats[n0 + wn * 64 + ni * 16 + lr], s);
                atomicAdd(&stats[DD + n0 + wn * 64 + ni * 16 + lr], q);
            }
        }
    }
    __syncthreads();
    #pragma unroll
    for (int c = 0; c < 8; ++c) {
        int row = c * 8 + (lane >> 3);
        short8 v = *(const short8*)&eb[row * EP + (lane & 7) * 8];
        *(short8*)&Cb[(size_t)(m0 + wm * 64 + row) * ldc + n0 + wn * 64 + (lane & 7) * 8] = v;
    }
}

// Fold batch stats -> per-channel scale/shift. <<<2, 768>>>
__global__ void bn_params(const float* __restrict__ stats_a, const float* __restrict__ stats_v,
                          const float* __restrict__ g_a, const float* __restrict__ be_a,
                          const float* __restrict__ g_v, const float* __restrict__ be_v,
                          float* __restrict__ bnp_a, float* __restrict__ bnp_v)
{
    const int e = threadIdx.x;
    const float* st = (blockIdx.x == 0) ? stats_a : stats_v;
    const float* g  = (blockIdx.x == 0) ? g_a  : g_v;
    const float* be = (blockIdx.x == 0) ? be_a : be_v;
    float* bnp = (blockIdx.x == 0) ? bnp_a : bnp_v;
    float mean = st[e] * (1.0f / NROWS);
    float var  = st[DD + e] * (1.0f / NROWS) - mean * mean;
    float scale = g[e] * rsqrtf(var + 1e-5f);
    bnp[e]      = scale;
    bnp[DD + e] = be[e] - mean * scale;
}

// BN affine + PReLU (x2) + residual + row LayerNorm -> f32 out. One block per (l,b) row.
__global__ __launch_bounds__(256)
void final_kernel(const float* __restrict__ x,
                  const u16* __restrict__ y_a, const u16* __restrict__ y_v,
                  const float* __restrict__ bnp_a, const float* __restrict__ bnp_v,
                  const float* __restrict__ pra, const float* __restrict__ prv,
                  const float* __restrict__ lng, const float* __restrict__ lnb,
                  float* __restrict__ out)
{
    const int n = blockIdx.x;
    const int tid = threadIdx.x;
    __shared__ float vrow[DD];
    __shared__ float reds[4], reds2[4];
    const float aa = pra[0];
    const float av = prv[0];
    const size_t base = (size_t)n * DD;
    float s = 0.f, s2 = 0.f;
    for (int e = tid; e < DD; e += 256) {
        float ya = bf2f(y_a[base + e]) * bnp_a[e] + bnp_a[DD + e];
        ya = ya > 0.f ? ya : aa * ya;
        float yv = bf2f(y_v[base + e]) * bnp_v[e] + bnp_v[DD + e];
        yv = yv > 0.f ? yv : av * yv;
        float v = x[base + e] + ya + yv;
        vrow[e] = v;
        s += v; s2 += v * v;
    }
    for (int off = 32; off > 0; off >>= 1) { s += __shfl_xor(s, off); s2 += __shfl_xor(s2, off); }
    const int wv = tid >> 6;
    if ((tid & 63) == 0) { reds[wv] = s; reds2[wv] = s2; }
    __syncthreads();
    float ts  = reds[0] + reds[1] + reds[2] + reds[3];
    float ts2 = reds2[0] + reds2[1] + reds2[2] + reds2[3];
    float mean = ts * (1.0f / DD);
    float var  = ts2 * (1.0f / DD) - mean * mean;
    float rstd = rsqrtf(var + 1e-5f);
    for (int e = tid; e < DD; e += 256) {
        float o = (vrow[e] - mean) * rstd * lng[e] + lnb[e];
        out[base + e] = o;
    }
}

extern "C" void kernel_launch(void* const* d_in, const int* in_sizes, int n_in,
                              void* d_out, int out_size, void* d_ws, size_t ws_size,
                              hipStream_t stream)
{
    const float* x_a    = (const float*)d_in[0];
    const float* x_v    = (const float*)d_in[1];
    const float* x      = (const float*)d_in[2];
    const float* W_a    = (const float*)d_in[3];
    const float* b_a    = (const float*)d_in[4];
    const float* bn_a_g = (const float*)d_in[5];
    const float* bn_a_b = (const float*)d_in[6];
    const float* pr_a   = (const float*)d_in[7];
    const float* W_v    = (const float*)d_in[8];
    const float* b_v    = (const float*)d_in[9];
    const float* bn_v_g = (const float*)d_in[10];
    const float* bn_v_b = (const float*)d_in[11];
    const float* pr_v   = (const float*)d_in[12];
    const float* ln_g   = (const float*)d_in[13];
    const float* ln_b   = (const float*)d_in[14];

    // ---- workspace layout ----
    float* stats_a = (float*)d_ws;                 // 1536
    float* stats_v = stats_a + 1536;               // 1536
    float* bnp_a   = stats_v + 1536;               // 1536
    float* bnp_v   = bnp_a + 1536;                 // 1536
    float* lsum    = bnp_v + 1536;                 // 8*2048
    u16* y_a = (u16*)(lsum + 8 * 2048);            // NROWS*DD bf16
    u16* y_v = y_a + (size_t)NROWS * DD;
    u16* UT  = y_v + (size_t)NROWS * DD;           // nb * 768*2048 bf16
    size_t fixed_bytes = (size_t)((char*)UT - (char*)d_ws);

    int nb = 1;
    for (int cand = 8; cand >= 1; cand >>= 1) {
        size_t need = fixed_bytes + (size_t)cand * (3145728ull + 8388608ull);
        if (need <= ws_size) { nb = cand; break; }
    }
    u16* P = UT + (size_t)nb * (768 * 2048);       // nb * 2048*2048 bf16

    hipMemsetAsync(stats_a, 0, 3072 * sizeof(float), stream);

    const float* KVs[2]   = { x_a, x_v };
    const float* Ws[2]    = { W_a, W_v };
    const float* BIs[2]   = { b_a, b_v };
    u16*         Ys[2]    = { y_a, y_v };
    float*       STs[2]   = { stats_a, stats_v };

    for (int br = 0; br < 2; ++br) {
        const float* kv = KVs[br];
        for (int c0 = 0; c0 < 8; c0 += nb) {
            // K0: U^T[e,m] = W @ KV^T   (M=768, N=2048, K=768)
            gemm_bt<0, float, float><<<dim3(16, 6, nb), 256, 0, stream>>>(
                Ws[br], DD, 0, kv + c0 * DD, BB * DD, DD,
                UT, (long)768 * 2048, 2048, DD, nullptr, nullptr, nullptr);
            hipMemsetAsync(lsum, 0, (size_t)nb * 2048 * sizeof(float), stream);
            // K1: P = exp(scale * Q @ KV^T)  (M=2048, N=2048, K=768) + row sums
            gemm_bt<1, float, float><<<dim3(16, 16, nb), 256, 0, stream>>>(
                x + c0 * DD, BB * DD, DD, kv + c0 * DD, BB * DD, DD,
                P, (long)2048 * 2048, 2048, DD, lsum, nullptr, nullptr);
            // K2: y = (P @ U^T)/l + bias  (M=2048, N=768, K=2048) + BN stats
            gemm_bt<2, u16, u16><<<dim3(6, 16, nb), 256, 0, stream>>>(
                P, 2048, (long)2048 * 2048, UT, 2048, (long)768 * 2048,
                Ys[br] + (size_t)c0 * DD, DD, BB * DD, 2048, lsum, BIs[br], STs[br]);
        }
    }

    bn_params<<<2, 768, 0, stream>>>(stats_a, stats_v, bn_a_g, bn_a_b, bn_v_g, bn_v_b, bnp_a, bnp_v);
    final_kernel<<<NROWS, 256, 0, stream>>>(x, y_a, y_v, bnp_a, bnp_v, pr_a, pr_v, ln_g, ln_b,
                                            (float*)d_out);
}

// Round 4
// 696.784 us; speedup vs baseline: 34.4072x; 1.1198x over previous
//
#include <hip/hip_runtime.h>
#include <stdint.h>

#define LL 2048
#define BB 8
#define DD 768
#define NROWS (LL*BB)
#define QKSCALE 0.03608439182435161f   // 1/sqrt(768)
#define EP 72                          // epilogue LDS row stride (bf16 elems)

typedef __attribute__((ext_vector_type(8))) short short8;
typedef __attribute__((ext_vector_type(4))) float f32x4;
typedef unsigned short u16;
typedef unsigned int u32;

__device__ __forceinline__ float bf2f(u16 u) {
    union { u32 u; float f; } c; c.u = ((u32)u) << 16; return c.f;
}
__device__ __forceinline__ u16 f2bf(float f) {
    union { float f; u32 u; } c; c.f = f;
    return (u16)((c.u + 0x8000u) >> 16);
}

// f32 -> bf16 bulk convert. blockIdx.y selects tensor; grid-stride over float4 groups.
__global__ __launch_bounds__(256)
void cvt_kernel(const float* __restrict__ s0, u16* __restrict__ d0,
                const float* __restrict__ s1, u16* __restrict__ d1,
                const float* __restrict__ s2, u16* __restrict__ d2,
                const float* __restrict__ s3, u16* __restrict__ d3,
                const float* __restrict__ s4, u16* __restrict__ d4,
                int nbig4, int nsmall4)
{
    const float* src; u16* dst; int n4;
    switch (blockIdx.y) {
        case 0: src = s0; dst = d0; n4 = nbig4; break;
        case 1: src = s1; dst = d1; n4 = nbig4; break;
        case 2: src = s2; dst = d2; n4 = nbig4; break;
        case 3: src = s3; dst = d3; n4 = nsmall4; break;
        default: src = s4; dst = d4; n4 = nsmall4; break;
    }
    for (int i = blockIdx.x * 256 + threadIdx.x; i < n4; i += gridDim.x * 256) {
        float4 v = *(const float4*)&src[i * 4];
        ushort4 o;
        o.x = f2bf(v.x); o.y = f2bf(v.y); o.z = f2bf(v.z); o.w = f2bf(v.w);
        *(ushort4*)&dst[i * 4] = o;
    }
}

// Async-stage one 128x32 bf16 tile into unpadded LDS [128][32].
// Wave w deposits row-blocks {2w, 2w+1} (16 rows each); lane -> (row=rb*16+lane/4, col=(lane&3)*8).
// LDS dst = base + rb*512 + lane*8 elems == wave-uniform base + lane*16B (required layout).
__device__ __forceinline__ void stage_async(u16* __restrict__ lds_base,
                                            const u16* __restrict__ g_base,
                                            long ld, int w, int lane)
{
    #pragma unroll
    for (int p = 0; p < 2; ++p) {
        const int rb = w * 2 + p;
        const u16* g = g_base + (size_t)(rb * 16 + (lane >> 2)) * ld + (lane & 3) * 8;
        u16* l = lds_base + rb * 512 + lane * 8;
        __builtin_amdgcn_global_load_lds((const __attribute__((address_space(1))) u32*)g,
                                         (__attribute__((address_space(3))) u32*)l,
                                         16, 0, 0);
    }
}

// C = A @ B^T over K (all bf16), 128x128 tile per block, 256 threads (2x2 waves of 64x64).
// A: [M,K] rows at stride lda (+ z*astr). B: [N,K] rows at stride ldb (+ z*bstr).
// C: bf16 [M,N] at stride ldc (+ z*cstr).
// EPI 0: plain store (U^T).  EPI 1: v=exp(v*QKSCALE), row-sum atomics to lsum.
// EPI 2: v=v*(1/lsum[row]) + bias[col]; BN col-stat atomics to stats.
template<int EPI>
__global__ __launch_bounds__(256)
void gemm_bt(const u16* __restrict__ A, int lda, long astr,
             const u16* __restrict__ B, int ldb, long bstr,
             u16* __restrict__ C, long cstr, int ldc,
             int K,
             float* __restrict__ lsum,
             const float* __restrict__ bias,
             float* __restrict__ stats)
{
    __shared__ u16 lds[18432];          // 36.9 KB: As(4096)+Bs(4096) in loop; 4x64x72 epilogue
    u16* As = lds;
    u16* Bs = lds + 4096;

    const int tid = threadIdx.x;
    const int z = blockIdx.z;
    const int m0 = blockIdx.y * 128, n0 = blockIdx.x * 128;
    const u16* Ab = A + (size_t)z * astr + (size_t)m0 * lda;
    const u16* Bb = B + (size_t)z * bstr + (size_t)n0 * ldb;
    u16* Cb = C + (size_t)z * cstr;

    const int lane = tid & 63, w = tid >> 6;
    const int wm = w >> 1, wn = w & 1;
    const int lr = lane & 15, lg = lane >> 4;

    f32x4 acc[4][4];
    const f32x4 zz = {0.f, 0.f, 0.f, 0.f};
    #pragma unroll
    for (int i = 0; i < 4; ++i)
        #pragma unroll
        for (int j = 0; j < 4; ++j) acc[i][j] = zz;

    for (int kt = 0; kt < K; kt += 32) {
        __syncthreads();
        stage_async(As, Ab + kt, lda, w, lane);
        stage_async(Bs, Bb + kt, ldb, w, lane);
        __syncthreads();                // emits s_waitcnt vmcnt(0) before s_barrier
        short8 af[4], bf[4];
        #pragma unroll
        for (int mi = 0; mi < 4; ++mi)
            af[mi] = *(const short8*)&As[(wm * 64 + mi * 16 + lr) * 32 + lg * 8];
        #pragma unroll
        for (int ni = 0; ni < 4; ++ni)
            bf[ni] = *(const short8*)&Bs[(wn * 64 + ni * 16 + lr) * 32 + lg * 8];
        #pragma unroll
        for (int mi = 0; mi < 4; ++mi)
            #pragma unroll
            for (int ni = 0; ni < 4; ++ni)
                acc[mi][ni] = __builtin_amdgcn_mfma_f32_16x16x32_bf16(af[mi], bf[ni], acc[mi][ni], 0, 0, 0);
    }

    // ---- epilogue: frags -> per-wave LDS tile (64x72) -> coalesced bf16 stores ----
    __syncthreads();
    u16* eb = lds + w * (64 * EP);

    float invl[4][4]; float bcol[4];
    if constexpr (EPI == 2) {
        #pragma unroll
        for (int mi = 0; mi < 4; ++mi)
            #pragma unroll
            for (int r = 0; r < 4; ++r)
                invl[mi][r] = 1.0f / lsum[z * 2048 + m0 + wm * 64 + mi * 16 + lg * 4 + r];
        #pragma unroll
        for (int ni = 0; ni < 4; ++ni)
            bcol[ni] = bias[n0 + wn * 64 + ni * 16 + lr];
    }
    float csum[4] = {0, 0, 0, 0}, csq[4] = {0, 0, 0, 0};

    #pragma unroll
    for (int mi = 0; mi < 4; ++mi) {
        float rsum[4] = {0, 0, 0, 0};
        #pragma unroll
        for (int ni = 0; ni < 4; ++ni) {
            #pragma unroll
            for (int r = 0; r < 4; ++r) {
                float v = acc[mi][ni][r];
                if constexpr (EPI == 1) { v = __expf(v * QKSCALE); rsum[r] += v; }
                if constexpr (EPI == 2) { v = v * invl[mi][r] + bcol[ni]; csum[ni] += v; csq[ni] += v * v; }
                eb[(mi * 16 + lg * 4 + r) * EP + ni * 16 + lr] = f2bf(v);
            }
        }
        if constexpr (EPI == 1) {
            #pragma unroll
            for (int r = 0; r < 4; ++r) {
                float s = rsum[r];
                s += __shfl_xor(s, 1); s += __shfl_xor(s, 2);
                s += __shfl_xor(s, 4); s += __shfl_xor(s, 8);
                if (lr == 0)
                    atomicAdd(&lsum[z * 2048 + m0 + wm * 64 + mi * 16 + lg * 4 + r], s);
            }
        }
    }
    if constexpr (EPI == 2) {
        #pragma unroll
        for (int ni = 0; ni < 4; ++ni) {
            float s = csum[ni], q = csq[ni];
            s += __shfl_xor(s, 16); s += __shfl_xor(s, 32);
            q += __shfl_xor(q, 16); q += __shfl_xor(q, 32);
            if (lg == 0) {
                atomicAdd(&stats[n0 + wn * 64 + ni * 16 + lr], s);
                atomicAdd(&stats[DD + n0 + wn * 64 + ni * 16 + lr], q);
            }
        }
    }
    __syncthreads();
    #pragma unroll
    for (int c = 0; c < 8; ++c) {
        int row = c * 8 + (lane >> 3);
        short8 v = *(const short8*)&eb[row * EP + (lane & 7) * 8];
        *(short8*)&Cb[(size_t)(m0 + wm * 64 + row) * ldc + n0 + wn * 64 + (lane & 7) * 8] = v;
    }
}

// Fold batch stats -> per-channel scale/shift. <<<2, 768>>>
__global__ void bn_params(const float* __restrict__ stats_a, const float* __restrict__ stats_v,
                          const float* __restrict__ g_a, const float* __restrict__ be_a,
                          const float* __restrict__ g_v, const float* __restrict__ be_v,
                          float* __restrict__ bnp_a, float* __restrict__ bnp_v)
{
    const int e = threadIdx.x;
    const float* st = (blockIdx.x == 0) ? stats_a : stats_v;
    const float* g  = (blockIdx.x == 0) ? g_a  : g_v;
    const float* be = (blockIdx.x == 0) ? be_a : be_v;
    float* bnp = (blockIdx.x == 0) ? bnp_a : bnp_v;
    float mean = st[e] * (1.0f / NROWS);
    float var  = st[DD + e] * (1.0f / NROWS) - mean * mean;
    float scale = g[e] * rsqrtf(var + 1e-5f);
    bnp[e]      = scale;
    bnp[DD + e] = be[e] - mean * scale;
}

// BN affine + PReLU (x2) + residual + row LayerNorm -> f32 out. One block per (l,b) row.
__global__ __launch_bounds__(256)
void final_kernel(const float* __restrict__ x,
                  const u16* __restrict__ y_a, const u16* __restrict__ y_v,
                  const float* __restrict__ bnp_a, const float* __restrict__ bnp_v,
                  const float* __restrict__ pra, const float* __restrict__ prv,
                  const float* __restrict__ lng, const float* __restrict__ lnb,
                  float* __restrict__ out)
{
    const int n = blockIdx.x;
    const int tid = threadIdx.x;
    __shared__ float vrow[DD];
    __shared__ float reds[4], reds2[4];
    const float aa = pra[0];
    const float av = prv[0];
    const size_t base = (size_t)n * DD;
    float s = 0.f, s2 = 0.f;
    for (int e = tid; e < DD; e += 256) {
        float ya = bf2f(y_a[base + e]) * bnp_a[e] + bnp_a[DD + e];
        ya = ya > 0.f ? ya : aa * ya;
        float yv = bf2f(y_v[base + e]) * bnp_v[e] + bnp_v[DD + e];
        yv = yv > 0.f ? yv : av * yv;
        float v = x[base + e] + ya + yv;
        vrow[e] = v;
        s += v; s2 += v * v;
    }
    for (int off = 32; off > 0; off >>= 1) { s += __shfl_xor(s, off); s2 += __shfl_xor(s2, off); }
    const int wv = tid >> 6;
    if ((tid & 63) == 0) { reds[wv] = s; reds2[wv] = s2; }
    __syncthreads();
    float ts  = reds[0] + reds[1] + reds[2] + reds[3];
    float ts2 = reds2[0] + reds2[1] + reds2[2] + reds2[3];
    float mean = ts * (1.0f / DD);
    float var  = ts2 * (1.0f / DD) - mean * mean;
    float rstd = rsqrtf(var + 1e-5f);
    for (int e = tid; e < DD; e += 256) {
        float o = (vrow[e] - mean) * rstd * lng[e] + lnb[e];
        out[base + e] = o;
    }
}

extern "C" void kernel_launch(void* const* d_in, const int* in_sizes, int n_in,
                              void* d_out, int out_size, void* d_ws, size_t ws_size,
                              hipStream_t stream)
{
    const float* x_a    = (const float*)d_in[0];
    const float* x_v    = (const float*)d_in[1];
    const float* x      = (const float*)d_in[2];
    const float* W_a    = (const float*)d_in[3];
    const float* b_a    = (const float*)d_in[4];
    const float* bn_a_g = (const float*)d_in[5];
    const float* bn_a_b = (const float*)d_in[6];
    const float* pr_a   = (const float*)d_in[7];
    const float* W_v    = (const float*)d_in[8];
    const float* b_v    = (const float*)d_in[9];
    const float* bn_v_g = (const float*)d_in[10];
    const float* bn_v_b = (const float*)d_in[11];
    const float* pr_v   = (const float*)d_in[12];
    const float* ln_g   = (const float*)d_in[13];
    const float* ln_b   = (const float*)d_in[14];

    // ---- workspace layout ----
    float* stats_a = (float*)d_ws;                 // 1536
    float* stats_v = stats_a + 1536;               // 1536
    float* bnp_a   = stats_v + 1536;               // 1536
    float* bnp_v   = bnp_a + 1536;                 // 1536
    float* lsum    = bnp_v + 1536;                 // 8*2048
    u16* xq_bf = (u16*)(lsum + 8 * 2048);          // NROWS*DD bf16
    u16* xa_bf = xq_bf + (size_t)NROWS * DD;       // NROWS*DD bf16, aliased as y_a
    u16* xv_bf = xa_bf + (size_t)NROWS * DD;       // NROWS*DD bf16, aliased as y_v
    u16* Wa_bf = xv_bf + (size_t)NROWS * DD;       // DD*DD
    u16* Wv_bf = Wa_bf + (size_t)DD * DD;          // DD*DD
    u16* UT    = Wv_bf + (size_t)DD * DD;          // nb * 768*2048 bf16
    u16* y_a = xa_bf;                              // alias: K2 writes after last kv read
    u16* y_v = xv_bf;
    size_t fixed_bytes = (size_t)((char*)UT - (char*)d_ws);

    int nb = 1;
    for (int cand = 8; cand >= 1; cand >>= 1) {
        size_t need = fixed_bytes + (size_t)cand * (3145728ull + 8388608ull);
        if (need <= ws_size) { nb = cand; break; }
    }
    u16* P = UT + (size_t)nb * (768 * 2048);       // nb * 2048*2048 bf16

    hipMemsetAsync(stats_a, 0, 3072 * sizeof(float), stream);

    // ---- bulk f32 -> bf16 conversion (x, x_a, x_v, W_a, W_v) ----
    cvt_kernel<<<dim3(3072, 5), 256, 0, stream>>>(
        x, xq_bf, x_a, xa_bf, x_v, xv_bf, W_a, Wa_bf, W_v, Wv_bf,
        NROWS * DD / 4, DD * DD / 4);

    const u16*   KVs[2]   = { xa_bf, xv_bf };
    const u16*   Ws[2]    = { Wa_bf, Wv_bf };
    const float* BIs[2]   = { b_a, b_v };
    u16*         Ys[2]    = { y_a, y_v };
    float*       STs[2]   = { stats_a, stats_v };

    for (int br = 0; br < 2; ++br) {
        const u16* kv = KVs[br];
        for (int c0 = 0; c0 < 8; c0 += nb) {
            // K0: U^T[e,m] = W @ KV^T   (M=768, N=2048, K=768)
            gemm_bt<0><<<dim3(16, 6, nb), 256, 0, stream>>>(
                Ws[br], DD, 0, kv + c0 * DD, BB * DD, DD,
                UT, (long)768 * 2048, 2048, DD, nullptr, nullptr, nullptr);
            hipMemsetAsync(lsum, 0, (size_t)nb * 2048 * sizeof(float), stream);
            // K1: P = exp(scale * Q @ KV^T)  (M=2048, N=2048, K=768) + row sums
            gemm_bt<1><<<dim3(16, 16, nb), 256, 0, stream>>>(
                xq_bf + c0 * DD, BB * DD, DD, kv + c0 * DD, BB * DD, DD,
                P, (long)2048 * 2048, 2048, DD, lsum, nullptr, nullptr);
            // K2: y = (P @ U^T)/l + bias  (M=2048, N=768, K=2048) + BN stats
            gemm_bt<2><<<dim3(6, 16, nb), 256, 0, stream>>>(
                P, 2048, (long)2048 * 2048, UT, 2048, (long)768 * 2048,
                Ys[br] + (size_t)c0 * DD, DD, BB * DD, 2048, lsum, BIs[br], STs[br]);
        }
    }

    bn_params<<<2, 768, 0, stream>>>(stats_a, stats_v, bn_a_g, bn_a_b, bn_v_g, bn_v_b, bnp_a, bnp_v);
    final_kernel<<<NROWS, 256, 0, stream>>>(x, y_a, y_v, bnp_a, bnp_v, pr_a, pr_v, ln_g, ln_b,
                                            (float*)d_out);
}

// Round 5
// 588.728 us; speedup vs baseline: 40.7224x; 1.1835x over previous
//
#include <hip/hip_runtime.h>
#include <stdint.h>

#define LL 2048
#define BB 8
#define DD 768
#define NROWS (LL*BB)
#define QKSCALE 0.03608439182435161f   // 1/sqrt(768)
#define EP 72                          // epilogue LDS row stride (bf16 elems)

typedef __attribute__((ext_vector_type(8))) short short8;
typedef __attribute__((ext_vector_type(4))) float f32x4;
typedef unsigned short u16;
typedef unsigned int u32;

__device__ __forceinline__ float bf2f(u16 u) {
    union { u32 u; float f; } c; c.u = ((u32)u) << 16; return c.f;
}
__device__ __forceinline__ u16 f2bf(float f) {
    union { float f; u32 u; } c; c.f = f;
    return (u16)((c.u + 0x8000u) >> 16);
}

// f32 -> bf16 bulk convert. blockIdx.y selects tensor; grid-stride over float4 groups.
__global__ __launch_bounds__(256)
void cvt_kernel(const float* __restrict__ s0, u16* __restrict__ d0,
                const float* __restrict__ s1, u16* __restrict__ d1,
                const float* __restrict__ s2, u16* __restrict__ d2,
                const float* __restrict__ s3, u16* __restrict__ d3,
                const float* __restrict__ s4, u16* __restrict__ d4,
                int nbig4, int nsmall4)
{
    const float* src; u16* dst; int n4;
    switch (blockIdx.y) {
        case 0: src = s0; dst = d0; n4 = nbig4; break;
        case 1: src = s1; dst = d1; n4 = nbig4; break;
        case 2: src = s2; dst = d2; n4 = nbig4; break;
        case 3: src = s3; dst = d3; n4 = nsmall4; break;
        default: src = s4; dst = d4; n4 = nsmall4; break;
    }
    for (int i = blockIdx.x * 256 + threadIdx.x; i < n4; i += gridDim.x * 256) {
        float4 v = *(const float4*)&src[i * 4];
        ushort4 o;
        o.x = f2bf(v.x); o.y = f2bf(v.y); o.z = f2bf(v.z); o.w = f2bf(v.w);
        *(ushort4*)&dst[i * 4] = o;
    }
}

// C = A @ B^T over K (all bf16), 128x128 tile per block, BK=64, 256 threads.
// LDS tiles are XOR-swizzled: element group (row, gs) of the 128x64 tile lives at
// granule row*8 + (gs ^ (row&7)); global_load_lds-compatible (lane col = (lane&7)^(lane>>3)).
// EPI 0: plain store (U^T).  EPI 1: v=exp(v*QKSCALE), row-sum atomics to lsum.
// EPI 2: v=v*(1/lsum[row]) + bias[col]; BN col-stat atomics to stats.
// Block remap: supertiles of `sw` m-blocks walk n together (L2 reuse of B panels).
template<int EPI>
__global__ __launch_bounds__(256)
void gemm_bt(const u16* __restrict__ A, int lda, long astr,
             const u16* __restrict__ B, int ldb, long bstr,
             u16* __restrict__ C, long cstr, int ldc,
             int K, int sw,
             float* __restrict__ lsum,
             const float* __restrict__ bias,
             float* __restrict__ stats)
{
    __shared__ u16 lds[18432];          // 36.9 KB: As(8192)+Bs(8192) in loop; 4x64x72 epilogue
    u16* As = lds;
    u16* Bs = lds + 8192;

    const int tid = threadIdx.x;
    const int z = blockIdx.z;
    const int flat = blockIdx.y * gridDim.x + blockIdx.x;
    const int per = sw * gridDim.x;
    const int bm = (flat / per) * sw + (flat % sw);
    const int bn = (flat % per) / sw;
    const int m0 = bm * 128, n0 = bn * 128;

    const u16* Ab = A + (size_t)z * astr + (size_t)m0 * lda;
    const u16* Bb = B + (size_t)z * bstr + (size_t)n0 * ldb;
    u16* Cb = C + (size_t)z * cstr;

    const int lane = tid & 63, w = tid >> 6;
    const int wm = w >> 1, wn = w & 1;
    const int lr = lane & 15, lg = lane >> 4;
    const int srow = lane >> 3;                       // staging row within 8-row group
    const int coff = ((lane & 7) ^ srow) * 8;         // swizzled global col offset (elems)

    f32x4 acc[4][4];
    const f32x4 zz = {0.f, 0.f, 0.f, 0.f};
    #pragma unroll
    for (int i = 0; i < 4; ++i)
        #pragma unroll
        for (int j = 0; j < 4; ++j) acc[i][j] = zz;

    for (int kt = 0; kt < K; kt += 64) {
        __syncthreads();
        #pragma unroll
        for (int p = 0; p < 4; ++p) {
            const int rb = w * 4 + p;                 // 8-row group 0..15
            const u16* ga = Ab + (size_t)(rb * 8 + srow) * lda + kt + coff;
            const u16* gb = Bb + (size_t)(rb * 8 + srow) * ldb + kt + coff;
            u16* la = As + rb * 512 + lane * 8;
            u16* lb = Bs + rb * 512 + lane * 8;
            __builtin_amdgcn_global_load_lds((const __attribute__((address_space(1))) u32*)ga,
                                             (__attribute__((address_space(3))) u32*)la,
                                             16, 0, 0);
            __builtin_amdgcn_global_load_lds((const __attribute__((address_space(1))) u32*)gb,
                                             (__attribute__((address_space(3))) u32*)lb,
                                             16, 0, 0);
        }
        __syncthreads();                // drains vmcnt(0) once per 64-wide k-tile
        #pragma unroll
        for (int ks = 0; ks < 2; ++ks) {
            short8 af[4], bf[4];
            #pragma unroll
            for (int mi = 0; mi < 4; ++mi)
                af[mi] = *(const short8*)&As[(wm * 64 + mi * 16 + lr) * 64 + (((ks * 4 + lg) ^ (lr & 7)) * 8)];
            #pragma unroll
            for (int ni = 0; ni < 4; ++ni)
                bf[ni] = *(const short8*)&Bs[(wn * 64 + ni * 16 + lr) * 64 + (((ks * 4 + lg) ^ (lr & 7)) * 8)];
            #pragma unroll
            for (int mi = 0; mi < 4; ++mi)
                #pragma unroll
                for (int ni = 0; ni < 4; ++ni)
                    acc[mi][ni] = __builtin_amdgcn_mfma_f32_16x16x32_bf16(af[mi], bf[ni], acc[mi][ni], 0, 0, 0);
        }
    }

    // ---- epilogue: frags -> per-wave LDS tile (64x72) -> coalesced bf16 stores ----
    __syncthreads();
    u16* eb = lds + w * (64 * EP);

    float invl[4][4]; float bcol[4];
    if constexpr (EPI == 2) {
        #pragma unroll
        for (int mi = 0; mi < 4; ++mi)
            #pragma unroll
            for (int r = 0; r < 4; ++r)
                invl[mi][r] = 1.0f / lsum[z * 2048 + m0 + wm * 64 + mi * 16 + lg * 4 + r];
        #pragma unroll
        for (int ni = 0; ni < 4; ++ni)
            bcol[ni] = bias[n0 + wn * 64 + ni * 16 + lr];
    }
    float csum[4] = {0, 0, 0, 0}, csq[4] = {0, 0, 0, 0};

    #pragma unroll
    for (int mi = 0; mi < 4; ++mi) {
        float rsum[4] = {0, 0, 0, 0};
        #pragma unroll
        for (int ni = 0; ni < 4; ++ni) {
            #pragma unroll
            for (int r = 0; r < 4; ++r) {
                float v = acc[mi][ni][r];
                if constexpr (EPI == 1) { v = __expf(v * QKSCALE); rsum[r] += v; }
                if constexpr (EPI == 2) { v = v * invl[mi][r] + bcol[ni]; csum[ni] += v; csq[ni] += v * v; }
                eb[(mi * 16 + lg * 4 + r) * EP + ni * 16 + lr] = f2bf(v);
            }
        }
        if constexpr (EPI == 1) {
            #pragma unroll
            for (int r = 0; r < 4; ++r) {
                float s = rsum[r];
                s += __shfl_xor(s, 1); s += __shfl_xor(s, 2);
                s += __shfl_xor(s, 4); s += __shfl_xor(s, 8);
                if (lr == 0)
                    atomicAdd(&lsum[z * 2048 + m0 + wm * 64 + mi * 16 + lg * 4 + r], s);
            }
        }
    }
    if constexpr (EPI == 2) {
        #pragma unroll
        for (int ni = 0; ni < 4; ++ni) {
            float s = csum[ni], q = csq[ni];
            s += __shfl_xor(s, 16); s += __shfl_xor(s, 32);
            q += __shfl_xor(q, 16); q += __shfl_xor(q, 32);
            if (lg == 0) {
                atomicAdd(&stats[n0 + wn * 64 + ni * 16 + lr], s);
                atomicAdd(&stats[DD + n0 + wn * 64 + ni * 16 + lr], q);
            }
        }
    }
    __syncthreads();
    #pragma unroll
    for (int c = 0; c < 8; ++c) {
        int row = c * 8 + (lane >> 3);
        short8 v = *(const short8*)&eb[row * EP + (lane & 7) * 8];
        *(short8*)&Cb[(size_t)(m0 + wm * 64 + row) * ldc + n0 + wn * 64 + (lane & 7) * 8] = v;
    }
}

// Fold batch stats -> per-channel scale/shift. <<<2, 768>>>
__global__ void bn_params(const float* __restrict__ stats_a, const float* __restrict__ stats_v,
                          const float* __restrict__ g_a, const float* __restrict__ be_a,
                          const float* __restrict__ g_v, const float* __restrict__ be_v,
                          float* __restrict__ bnp_a, float* __restrict__ bnp_v)
{
    const int e = threadIdx.x;
    const float* st = (blockIdx.x == 0) ? stats_a : stats_v;
    const float* g  = (blockIdx.x == 0) ? g_a  : g_v;
    const float* be = (blockIdx.x == 0) ? be_a : be_v;
    float* bnp = (blockIdx.x == 0) ? bnp_a : bnp_v;
    float mean = st[e] * (1.0f / NROWS);
    float var  = st[DD + e] * (1.0f / NROWS) - mean * mean;
    float scale = g[e] * rsqrtf(var + 1e-5f);
    bnp[e]      = scale;
    bnp[DD + e] = be[e] - mean * scale;
}

// BN affine + PReLU (x2) + residual + row LayerNorm -> f32 out. One block per (l,b) row.
__global__ __launch_bounds__(256)
void final_kernel(const float* __restrict__ x,
                  const u16* __restrict__ y_a, const u16* __restrict__ y_v,
                  const float* __restrict__ bnp_a, const float* __restrict__ bnp_v,
                  const float* __restrict__ pra, const float* __restrict__ prv,
                  const float* __restrict__ lng, const float* __restrict__ lnb,
                  float* __restrict__ out)
{
    const int n = blockIdx.x;
    const int tid = threadIdx.x;
    __shared__ float vrow[DD];
    __shared__ float reds[4], reds2[4];
    const float aa = pra[0];
    const float av = prv[0];
    const size_t base = (size_t)n * DD;
    float s = 0.f, s2 = 0.f;
    for (int e = tid; e < DD; e += 256) {
        float ya = bf2f(y_a[base + e]) * bnp_a[e] + bnp_a[DD + e];
        ya = ya > 0.f ? ya : aa * ya;
        float yv = bf2f(y_v[base + e]) * bnp_v[e] + bnp_v[DD + e];
        yv = yv > 0.f ? yv : av * yv;
        float v = x[base + e] + ya + yv;
        vrow[e] = v;
        s += v; s2 += v * v;
    }
    for (int off = 32; off > 0; off >>= 1) { s += __shfl_xor(s, off); s2 += __shfl_xor(s2, off); }
    const int wv = tid >> 6;
    if ((tid & 63) == 0) { reds[wv] = s; reds2[wv] = s2; }
    __syncthreads();
    float ts  = reds[0] + reds[1] + reds[2] + reds[3];
    float ts2 = reds2[0] + reds2[1] + reds2[2] + reds2[3];
    float mean = ts * (1.0f / DD);
    float var  = ts2 * (1.0f / DD) - mean * mean;
    float rstd = rsqrtf(var + 1e-5f);
    for (int e = tid; e < DD; e += 256) {
        float o = (vrow[e] - mean) * rstd * lng[e] + lnb[e];
        out[base + e] = o;
    }
}

extern "C" void kernel_launch(void* const* d_in, const int* in_sizes, int n_in,
                              void* d_out, int out_size, void* d_ws, size_t ws_size,
                              hipStream_t stream)
{
    const float* x_a    = (const float*)d_in[0];
    const float* x_v    = (const float*)d_in[1];
    const float* x      = (const float*)d_in[2];
    const float* W_a    = (const float*)d_in[3];
    const float* b_a    = (const float*)d_in[4];
    const float* bn_a_g = (const float*)d_in[5];
    const float* bn_a_b = (const float*)d_in[6];
    const float* pr_a   = (const float*)d_in[7];
    const float* W_v    = (const float*)d_in[8];
    const float* b_v    = (const float*)d_in[9];
    const float* bn_v_g = (const float*)d_in[10];
    const float* bn_v_b = (const float*)d_in[11];
    const float* pr_v   = (const float*)d_in[12];
    const float* ln_g   = (const float*)d_in[13];
    const float* ln_b   = (const float*)d_in[14];

    // ---- workspace layout ----
    float* stats_a = (float*)d_ws;                 // 1536
    float* stats_v = stats_a + 1536;               // 1536
    float* bnp_a   = stats_v + 1536;               // 1536
    float* bnp_v   = bnp_a + 1536;                 // 1536
    float* lsum    = bnp_v + 1536;                 // 16*2048 (both branches)
    u16* xq_bf = (u16*)(lsum + 16 * 2048);         // NROWS*DD bf16
    u16* xa_bf = xq_bf + (size_t)NROWS * DD;       // NROWS*DD bf16, aliased as y_a
    u16* xv_bf = xa_bf + (size_t)NROWS * DD;       // NROWS*DD bf16, aliased as y_v
    u16* Wa_bf = xv_bf + (size_t)NROWS * DD;       // DD*DD
    u16* Wv_bf = Wa_bf + (size_t)DD * DD;          // DD*DD
    u16* UT    = Wv_bf + (size_t)DD * DD;          // nb * 768*2048 bf16
    u16* y_a = xa_bf;                              // alias: K2 writes after last kv read
    u16* y_v = xv_bf;
    size_t fixed_bytes = (size_t)((char*)UT - (char*)d_ws);

    int nb = 1;
    for (int cand = 8; cand >= 1; cand >>= 1) {
        size_t need = fixed_bytes + (size_t)cand * (3145728ull + 8388608ull);
        if (need <= ws_size) { nb = cand; break; }
    }
    u16* P = UT + (size_t)nb * (768 * 2048);       // nb * 2048*2048 bf16

    // zero BN stat accumulators + all lsum slots once up front
    hipMemsetAsync(stats_a, 0, (3072 + 4 * 1536 - 3072 + 16 * 2048) * 0 + (3072 + 16 * 2048 + 3072) * sizeof(float), stream);
    // (layout is contiguous: stats_a, stats_v, bnp_a, bnp_v, lsum -> zero through lsum)

    // ---- bulk f32 -> bf16 conversion (x, x_a, x_v, W_a, W_v) ----
    cvt_kernel<<<dim3(3072, 5), 256, 0, stream>>>(
        x, xq_bf, x_a, xa_bf, x_v, xv_bf, W_a, Wa_bf, W_v, Wv_bf,
        NROWS * DD / 4, DD * DD / 4);

    const u16*   KVs[2]   = { xa_bf, xv_bf };
    const u16*   Ws[2]    = { Wa_bf, Wv_bf };
    const float* BIs[2]   = { b_a, b_v };
    u16*         Ys[2]    = { y_a, y_v };
    float*       STs[2]   = { stats_a, stats_v };

    for (int br = 0; br < 2; ++br) {
        const u16* kv = KVs[br];
        for (int c0 = 0; c0 < 8; c0 += nb) {
            float* lsum_bc = (nb == 8) ? (lsum + br * 8 * 2048) : lsum;
            if (nb != 8)
                hipMemsetAsync(lsum, 0, (size_t)nb * 2048 * sizeof(float), stream);
            // K0: U^T[e,m] = W @ KV^T   (M=768, N=2048, K=768)
            gemm_bt<0><<<dim3(16, 6, nb), 256, 0, stream>>>(
                Ws[br], DD, 0, kv + c0 * DD, BB * DD, DD,
                UT, (long)768 * 2048, 2048, DD, 2, nullptr, nullptr, nullptr);
            // K1: P = exp(scale * Q @ KV^T)  (M=2048, N=2048, K=768) + row sums
            gemm_bt<1><<<dim3(16, 16, nb), 256, 0, stream>>>(
                xq_bf + c0 * DD, BB * DD, DD, kv + c0 * DD, BB * DD, DD,
                P, (long)2048 * 2048, 2048, DD, 4, lsum_bc, nullptr, nullptr);
            // K2: y = (P @ U^T)/l + bias  (M=2048, N=768, K=2048) + BN stats
            gemm_bt<2><<<dim3(6, 16, nb), 256, 0, stream>>>(
                P, 2048, (long)2048 * 2048, UT, 2048, (long)768 * 2048,
                Ys[br] + (size_t)c0 * DD, DD, BB * DD, 2048, 4, lsum_bc, BIs[br], STs[br]);
        }
    }

    bn_params<<<2, 768, 0, stream>>>(stats_a, stats_v, bn_a_g, bn_a_b, bn_v_g, bn_v_b, bnp_a, bnp_v);
    final_kernel<<<NROWS, 256, 0, stream>>>(x, y_a, y_v, bnp_a, bnp_v, pr_a, pr_v, ln_g, ln_b,
                                            (float*)d_out);
}